// Round 14
// baseline (420.787 us; speedup 1.0000x reference)
//
#include <hip/hip_runtime.h>
#include <math.h>
#include <stdint.h>

#define NBATCH 2
#define NC 80
#define CHN 256
#define HMM 128
#define HWN (HMM*HMM)
#define NCELL 3872
#define FLATN (NCELL*NC)
#define TOPN 500
#define SROWS 512
#define MAXM 100
#define OUTH 512
#define OUTW 512
#define NBINS 1024
#define CANDCAP 1024
#define BM 128
#define BN 128
#define BK 16
#define GNB (HWN/BN)   // 128 N-blocks per row

__device__ __forceinline__ float sigmoidf_(float x){ return 1.0f/(1.0f+expf(-x)); }
__device__ __forceinline__ unsigned short f2bf(float x){
  uint32_t u = __float_as_uint(x);
  uint32_t r = u + 0x7FFFu + ((u >> 16) & 1u);
  return (unsigned short)(r >> 16);
}
__device__ __forceinline__ float bf2f(unsigned short h){ return __uint_as_float(((uint32_t)h) << 16); }

__device__ __forceinline__ void cell_decode(int cell, int& lvl, int& g, int& y, int& x){
  int off;
  if (cell < 1600)      { lvl=0; g=40; off=0; }
  else if (cell < 2896) { lvl=1; g=36; off=1600; }
  else if (cell < 3472) { lvl=2; g=24; off=2896; }
  else if (cell < 3728) { lvl=3; g=16; off=3472; }
  else                  { lvl=4; g=12; off=3728; }
  int r = cell - off; y = r / g; x = r - y*g;
}

// Bitonic sort, descending; barrier only for j>=32 passes.
template<int N, int NT>
__device__ __forceinline__ void bitonic_desc(uint64_t* key){
  int tid = threadIdx.x;
  __syncthreads();
  for (int k = 2; k <= N; k <<= 1)
    for (int j = k >> 1; j > 0; j >>= 1) {
      if (j >= 32) __syncthreads();
      for (int e = tid; e < N; e += NT) {
        int l = e ^ j;
        if (l > e) {
          uint64_t a = key[e], c = key[l];
          bool up = ((e & k) == 0);
          if (up ? (a < c) : (a > c)) { key[e] = c; key[l] = a; }
        }
      }
    }
  __syncthreads();
}

// c-major ordering; per-block LDS histogram.
__global__ void k1_scores(const float* __restrict__ c0, const float* __restrict__ c1,
                          const float* __restrict__ c2, const float* __restrict__ c3,
                          const float* __restrict__ c4,
                          float* __restrict__ scores_t, uint32_t* __restrict__ hist){
  __shared__ uint32_t h[NBATCH*NBINS];
  int tid = threadIdx.x;
  for (int i = tid; i < NBATCH*NBINS; i += 256) h[i] = 0;
  __syncthreads();
  int t = blockIdx.x*blockDim.x + tid;
  if (t < NBATCH*FLATN) {
    int b = t / FLATN;
    int rem = t - b*FLATN;
    int c = rem / NCELL;
    int cell = rem - c*NCELL;
    int lvl,g,y,x; cell_decode(cell,lvl,g,y,x);
    const float* cp = lvl==0?c0:lvl==1?c1:lvl==2?c2:lvl==3?c3:c4;
    const float* base = cp + (size_t)(b*NC + c)*g*g;
    float raw = base[y*g + x];
    float m = raw;
    if (y > 0)          m = fmaxf(m, base[(y-1)*g + x]);
    if (x > 0)          m = fmaxf(m, base[y*g + x-1]);
    if (y > 0 && x > 0) m = fmaxf(m, base[(y-1)*g + x-1]);
    float s = (raw == m) ? sigmoidf_(raw) : 0.0f;
    scores_t[t] = s;
    if (s > 0.1f) {
      int bin = (int)(s * 1024.0f); if (bin > NBINS-1) bin = NBINS-1;
      atomicAdd(&h[b*NBINS + bin], 1u);
    }
  }
  __syncthreads();
  for (int i = tid; i < NBATCH*NBINS; i += 256) {
    uint32_t v = h[i];
    if (v) atomicAdd(&hist[i], v);
  }
}

__global__ __launch_bounds__(1024) void k2_cutoff(const uint32_t* __restrict__ hist, int* __restrict__ cutoff){
  __shared__ uint32_t h[NBINS];
  int b = blockIdx.x;
  h[threadIdx.x] = hist[b*NBINS + threadIdx.x];
  __syncthreads();
  if (threadIdx.x == 0) {
    int acc = 0; int cut = 0;
    for (int d = NBINS-1; d >= 0; --d) {
      acc += (int)h[d];
      if (acc >= TOPN) { cut = d; break; }
    }
    cutoff[b] = cut;
  }
}

__global__ void k3_gather(const float* __restrict__ scores_t, const int* __restrict__ cutoff,
                          uint32_t* __restrict__ cnt, float* __restrict__ cval, uint32_t* __restrict__ cidx){
  int t = blockIdx.x*blockDim.x + threadIdx.x;
  if (t >= NBATCH*FLATN) return;
  int b = t / FLATN;
  int rem = t - b*FLATN;
  int c = rem / NCELL;
  int cell = rem - c*NCELL;
  float v = scores_t[t];
  if (v > 0.1f) {
    int bin = (int)(v * 1024.0f); if (bin > NBINS-1) bin = NBINS-1;
    if (bin >= cutoff[b]) {
      uint32_t p = atomicAdd(&cnt[b], 1u);
      if (p < CANDCAP) { cval[b*CANDCAP+p] = v; cidx[b*CANDCAP+p] = (uint32_t)(cell*NC + c); }
    }
  }
}

__global__ __launch_bounds__(512) void k4_sort(const uint32_t* __restrict__ cnt,
        const float* __restrict__ cval, const uint32_t* __restrict__ cidx,
        float* __restrict__ vals, int* __restrict__ cellA, int* __restrict__ labelA){
  __shared__ uint64_t key[CANDCAP];
  int b = blockIdx.x; int tid = threadIdx.x;
  int n = (int)cnt[b]; if (n > CANDCAP) n = CANDCAP;
  for (int e = tid; e < CANDCAP; e += 512) {
    uint64_t k = 0;
    if (e < n)
      k = ((uint64_t)__float_as_uint(cval[b*CANDCAP+e]) << 32) |
          (uint64_t)(0xFFFFFFFFu - cidx[b*CANDCAP+e]);
    key[e] = k;
  }
  bitonic_desc<CANDCAP,512>(key);
  for (int r = tid; r < TOPN; r += 512) {
    uint64_t k = key[r];
    if ((k >> 32) == 0) { vals[b*TOPN+r] = -1.0f; cellA[b*TOPN+r] = 0; labelA[b*TOPN+r] = 0; }
    else {
      uint32_t idx = 0xFFFFFFFFu - (uint32_t)(k & 0xFFFFFFFFu);
      vals[b*TOPN+r]   = __uint_as_float((uint32_t)(k >> 32));
      cellA[b*TOPN+r]  = (int)(idx / NC);
      labelA[b*TOPN+r] = (int)(idx % NC);
    }
  }
}

__global__ void k5_kmat(const float* __restrict__ k0p, const float* __restrict__ k1p,
                        const float* __restrict__ k2p, const float* __restrict__ k3p,
                        const float* __restrict__ k4p,
                        const int* __restrict__ cellA, float* __restrict__ Kmat){
  int t = blockIdx.x*blockDim.x + threadIdx.x;
  if (t >= NBATCH*TOPN*CHN) return;
  int b = t / (TOPN*CHN); int rem = t - b*(TOPN*CHN);
  int k = rem / CHN; int c = rem - k*CHN;
  int cell = cellA[b*TOPN + k];
  int lvl,g,y,x; cell_decode(cell,lvl,g,y,x);
  const float* kp = lvl==0?k0p:lvl==1?k1p:lvl==2?k2p:lvl==3?k3p:k4p;
  Kmat[t] = kp[((size_t)(b*CHN + c)*g + y)*g + x];
}

// 128x128 tile, 8x8 micro-tile, BK=16. A staged in LDS (double-buffered, swizzled);
// B read DIRECTLY from global (L2/L3-resident mf, wave-dedup'd addresses) ->
// LDS pipe demand halves: 384 cyc/kk-slot vs 512 VALU -> VALU-bound.
__global__ __launch_bounds__(256) void k6_gemm1(const float* __restrict__ Kmat, const float* __restrict__ mf,
        unsigned short* __restrict__ sigb, uint32_t* __restrict__ bits,
        float* __restrict__ psum, float* __restrict__ pseg){
  __shared__ alignas(16) float As[2][BK][BM+4];
  int tid = threadIdx.x;
  int nb = blockIdx.x, mb = blockIdx.y, b = blockIdx.z;
  int row0 = mb*BM, col0 = nb*BN;
  int tx = tid & 15, ty = tid >> 4;

  int ar[2], aq[2];
  #pragma unroll
  for (int i = 0; i < 2; ++i) {
    int e = i*256 + tid;
    ar[i] = e >> 2; aq[i] = e & 3;
  }
  const float* mfb = mf + (size_t)b*CHN*HWN + col0 + tx*4;

  float4 pa[2];
  const float4 z4 = make_float4(0.f,0.f,0.f,0.f);
  #pragma unroll
  for (int i = 0; i < 2; ++i) {
    int rr = row0 + ar[i];
    pa[i] = (rr < TOPN) ? *(const float4*)&Kmat[((size_t)b*TOPN + rr)*CHN + aq[i]*4] : z4;
  }
  #pragma unroll
  for (int i = 0; i < 2; ++i) {
    int colA = ar[i] ^ (aq[i] << 2);
    As[0][aq[i]*4+0][colA] = pa[i].x;
    As[0][aq[i]*4+1][colA] = pa[i].y;
    As[0][aq[i]*4+2][colA] = pa[i].z;
    As[0][aq[i]*4+3][colA] = pa[i].w;
  }
  __syncthreads();

  float acc[8][8];
  #pragma unroll
  for (int i=0;i<8;i++)
    #pragma unroll
    for(int j=0;j<8;j++) acc[i][j]=0.f;

  int cur = 0;
  for (int k0 = 0; k0 < CHN; k0 += BK) {
    bool more = (k0 + BK < CHN);
    if (more) {
      int k0n = k0 + BK;
      #pragma unroll
      for (int i = 0; i < 2; ++i) {
        int rr = row0 + ar[i];
        pa[i] = (rr < TOPN) ? *(const float4*)&Kmat[((size_t)b*TOPN + rr)*CHN + k0n + aq[i]*4] : z4;
      }
    }
    #pragma unroll 8
    for (int kk = 0; kk < BK; ++kk) {
      const float* mfr = mfb + (size_t)(k0 + kk)*HWN;
      float4 b0 = *(const float4*)mfr;
      float4 b1 = *(const float4*)(mfr + 64);
      int s = (kk >> 2) << 2;
      float4 a0 = *(float4*)&As[cur][kk][(ty*8) ^ s];
      float4 a1 = *(float4*)&As[cur][kk][(ty*8+4) ^ s];
      float av[8] = {a0.x,a0.y,a0.z,a0.w,a1.x,a1.y,a1.z,a1.w};
      #pragma unroll
      for (int i = 0; i < 8; ++i) {
        acc[i][0] += av[i]*b0.x; acc[i][1] += av[i]*b0.y; acc[i][2] += av[i]*b0.z; acc[i][3] += av[i]*b0.w;
        acc[i][4] += av[i]*b1.x; acc[i][5] += av[i]*b1.y; acc[i][6] += av[i]*b1.z; acc[i][7] += av[i]*b1.w;
      }
    }
    if (more) {
      int nxt = cur ^ 1;
      #pragma unroll
      for (int i = 0; i < 2; ++i) {
        int colA = ar[i] ^ (aq[i] << 2);
        As[nxt][aq[i]*4+0][colA] = pa[i].x;
        As[nxt][aq[i]*4+1][colA] = pa[i].y;
        As[nxt][aq[i]*4+2][colA] = pa[i].z;
        As[nxt][aq[i]*4+3][colA] = pa[i].w;
      }
      __syncthreads();
      cur = nxt;
    }
  }
  // epilogue
  #pragma unroll
  for (int i = 0; i < 8; ++i) {
    int r = row0 + ty*8 + i;
    float se = 0.f; int cc = 0;
    #pragma unroll
    for (int q = 0; q < 2; ++q) {
      float4 sv;
      sv.x = sigmoidf_(acc[i][q*4+0]);
      sv.y = sigmoidf_(acc[i][q*4+1]);
      sv.z = sigmoidf_(acc[i][q*4+2]);
      sv.w = sigmoidf_(acc[i][q*4+3]);
      uint32_t m = 0;
      if (sv.x > 0.5f) { m |= 1u; se += sv.x; cc++; }
      if (sv.y > 0.5f) { m |= 2u; se += sv.y; cc++; }
      if (sv.z > 0.5f) { m |= 4u; se += sv.z; cc++; }
      if (sv.w > 0.5f) { m |= 8u; se += sv.w; cc++; }
      uint32_t wrd = m << ((tx & 7)*4);
      wrd |= __shfl_xor(wrd, 1);
      wrd |= __shfl_xor(wrd, 2);
      wrd |= __shfl_xor(wrd, 4);
      if ((tx & 7) == 0 && r < TOPN)
        bits[((size_t)b*TOPN + r)*512 + nb*4 + q*2 + (tx>>3)] = wrd;
      ushort4 sb;
      sb.x = f2bf(sv.x); sb.y = f2bf(sv.y); sb.z = f2bf(sv.z); sb.w = f2bf(sv.w);
      *(ushort4*)&sigb[((size_t)b*SROWS + r)*HWN + col0 + q*64 + tx*4] = sb;
    }
    #pragma unroll
    for (int d = 1; d < 16; d <<= 1) {
      se += __shfl_xor(se, d);
      cc += __shfl_xor(cc, d);
    }
    if (tx == 0 && r < TOPN) {
      psum[(size_t)nb*(NBATCH*TOPN) + b*TOPN + r] = (float)cc;
      pseg[(size_t)nb*(NBATCH*TOPN) + b*TOPN + r] = se;
    }
  }
}

// rowstats + order-sort; zeroes comp
__global__ __launch_bounds__(512) void k78_stats_order(const float* __restrict__ psum, const float* __restrict__ pseg,
        const float* __restrict__ vals, const int* __restrict__ cellA,
        float* __restrict__ summ, float* __restrict__ scores, int* __restrict__ keepA,
        int* __restrict__ order, float* __restrict__ comp){
  __shared__ uint64_t key[512];
  int b = blockIdx.x, tid = threadIdx.x;
  uint64_t k = 0;
  if (tid < TOPN) {
    int t = b*TOPN + tid;
    comp[t] = 0.f;
    float sc = 0.f, sg = 0.f;
    for (int i = 0; i < GNB; ++i) {
      sc += psum[(size_t)i*(NBATCH*TOPN) + t];
      sg += pseg[(size_t)i*(NBATCH*TOPN) + t];
    }
    float v = vals[t];
    int cell = cellA[t];
    int lvl,g,y,x; cell_decode(cell,lvl,g,y,x);
    float stride = (lvl<=1)?8.f:(lvl==2)?16.f:32.f;
    bool keep = (v > 0.1f) && (sc > stride);
    float seg = sg / fmaxf(sc, 1e-6f);
    summ[t] = sc;
    float s = keep ? v*seg : 0.f;
    scores[t] = s;
    keepA[t] = keep ? 1 : 0;
    k = ((uint64_t)__float_as_uint(s) << 32) | (uint64_t)(0xFFFFFFFFu - (uint32_t)tid);
  }
  key[tid] = k;
  bitonic_desc<512,512>(key);
  if (tid < TOPN) order[b*TOPN+tid] = (int)(0xFFFFFFFFu - (uint32_t)(key[tid] & 0xFFFFFFFFu));
}

// one block per (i,b); dense row-major dmat rows + comp[j] atomicMax
__global__ __launch_bounds__(256) void k9_dmat(const uint32_t* __restrict__ bitsG,
        const int* __restrict__ order, const int* __restrict__ labelA, const int* __restrict__ keepA,
        const float* __restrict__ summ, float* __restrict__ dmat, float* __restrict__ comp){
  __shared__ uint32_t rowb[512];
  int i = blockIdx.x, b = blockIdx.y, tid = threadIdx.x;
  int oi = order[b*TOPN + i];
  int keep_i = keepA[b*TOPN + oi];
  float si = summ[b*TOPN + oi];
  int li = labelA[b*TOPN + oi];
  if (keep_i)
    for (int w = tid; w < 512; w += 256) rowb[w] = bitsG[((size_t)b*TOPN + oi)*512 + w];
  __syncthreads();
  float* drow = dmat + ((size_t)b*TOPN + i)*TOPN;
  for (int j = tid; j < TOPN; j += 256) {
    float v = 0.f;
    if (keep_i && j > i) {
      int oj = order[b*TOPN + j];
      if (keepA[b*TOPN + oj] && labelA[b*TOPN + oj] == li) {
        const uint4* rj = (const uint4*)&bitsG[((size_t)b*TOPN + oj)*512];
        const uint4* ri = (const uint4*)rowb;
        int cc = 0;
        for (int w = 0; w < 128; ++w) {
          uint4 x = rj[w], y = ri[w];
          cc += __popc(x.x & y.x) + __popc(x.y & y.y) + __popc(x.z & y.z) + __popc(x.w & y.w);
        }
        float sj = summ[b*TOPN + oj];
        float inter = (float)cc;
        v = inter / fmaxf(si + sj - inter, 1e-6f);
      }
    }
    drow[j] = v;
    if (v > 0.f) atomicMax((int*)&comp[b*TOPN + j], __float_as_int(v));
  }
}

// single-pass coef: block (j,b), 512 threads, tid=i
__global__ __launch_bounds__(512) void k10_coef(const float* __restrict__ dmat, const float* __restrict__ comp,
        const float* __restrict__ scores, const int* __restrict__ order, const int* __restrict__ keepA,
        float* __restrict__ s2){
  __shared__ float red[8];
  int j = blockIdx.x, b = blockIdx.y, tid = threadIdx.x;
  float mn = 1e30f;
  if (tid < TOPN) {
    float d = dmat[((size_t)b*TOPN + tid)*TOPN + j];
    float c = comp[b*TOPN + tid];
    mn = expf(-2.0f*d*d) / expf(-2.0f*c*c);
  }
  #pragma unroll
  for (int d = 1; d < 64; d <<= 1) mn = fminf(mn, __shfl_xor(mn, d));
  if ((tid & 63) == 0) red[tid >> 6] = mn;
  __syncthreads();
  if (tid == 0) {
    mn = red[0];
    #pragma unroll
    for (int w = 1; w < 8; ++w) mn = fminf(mn, red[w]);
    int oj = order[b*TOPN+j];
    float s = scores[b*TOPN+oj] * mn;
    bool ok = (s >= 0.05f) && (s >= 0.1f) && (keepA[b*TOPN+oj] != 0);
    s2[b*TOPN+j] = ok ? s : 0.f;
  }
}

__global__ __launch_bounds__(512) void k11_top100(const float* __restrict__ s2, const int* __restrict__ order,
        const int* __restrict__ labelA, float* __restrict__ outF, int* __restrict__ selrow){
  __shared__ uint64_t key[512];
  int b = blockIdx.x, tid = threadIdx.x;
  uint64_t k = 0;
  if (tid < TOPN)
    k = ((uint64_t)__float_as_uint(s2[b*TOPN+tid]) << 32) | (uint64_t)(0xFFFFFFFFu - (uint32_t)tid);
  key[tid] = k;
  bitonic_desc<512,512>(key);
  if (tid < MAXM) {
    uint64_t kk = key[tid];
    float v = __uint_as_float((uint32_t)(kk >> 32));
    int j = (int)(0xFFFFFFFFu - (uint32_t)(kk & 0xFFFFFFFFu));
    if (j < 0 || j >= TOPN) { j = 0; v = 0.f; }
    int orow = order[b*TOPN + j];
    float lab = (v > 0.f) ? (float)labelA[b*TOPN + orow] : -1.0f;
    size_t maskCount = (size_t)NBATCH*MAXM*OUTH*OUTW;
    outF[maskCount + (size_t)b*MAXM + tid] = lab;
    outF[maskCount + (size_t)NBATCH*MAXM + (size_t)b*MAXM + tid] = v;
    selrow[b*MAXM + tid] = orow;
  }
}

__global__ void k13_upsample(const unsigned short* __restrict__ sigb, const int* __restrict__ selrow,
                             float* __restrict__ outF){
  int t = blockIdx.x*blockDim.x + threadIdx.x;
  const int XG = OUTW/4;
  int total = NBATCH*MAXM*OUTH*XG;
  if (t >= total) return;
  int xg = t % XG;
  int tmp = t / XG;
  int Y = tmp % OUTH;
  int tmp2 = tmp / OUTH;
  int r = tmp2 % MAXM;
  int b = tmp2 / MAXM;
  size_t maskCount = (size_t)NBATCH*MAXM*OUTH*OUTW;
  float fv = outF[maskCount + (size_t)NBATCH*MAXM + (size_t)b*MAXM + r];
  float4 o = make_float4(0.f,0.f,0.f,0.f);
  if (fv > 0.f) {
    const unsigned short* sm = sigb + ((size_t)b*SROWS + selrow[b*MAXM + r])*HWN;
    const float SC = (float)(127.0/511.0);
    float fy = (float)Y * SC;
    int ly = (int)floorf(fy); if (ly < 0) ly = 0; if (ly > HMM-1) ly = HMM-1;
    int hy = ly+1 < HMM ? ly+1 : HMM-1;
    float wy = fy - (float)ly;
    float res[4];
    #pragma unroll
    for (int u = 0; u < 4; ++u) {
      int X = xg*4 + u;
      float fx = (float)X * SC;
      int lx = (int)floorf(fx); if (lx < 0) lx = 0; if (lx > HMM-1) lx = HMM-1;
      int hx = lx+1 < HMM ? lx+1 : HMM-1;
      float wx = fx - (float)lx;
      float a = (1.f-wy)*bf2f(sm[ly*HMM+lx]) + wy*bf2f(sm[hy*HMM+lx]);
      float c = (1.f-wy)*bf2f(sm[ly*HMM+hx]) + wy*bf2f(sm[hy*HMM+hx]);
      float v = (1.f-wx)*a + wx*c;
      res[u] = (v > 0.5f) ? 1.f : 0.f;
    }
    o = make_float4(res[0],res[1],res[2],res[3]);
  }
  *(float4*)&outF[(((size_t)b*MAXM + r)*OUTH + Y)*OUTW + xg*4] = o;
}

extern "C" void kernel_launch(void* const* d_in, const int* in_sizes, int n_in,
                              void* d_out, int out_size, void* d_ws, size_t ws_size,
                              hipStream_t stream) {
  const float* mf = (const float*)d_in[0];
  const float *cate[5], *kern[5];
  bool interleaved = (n_in > 2) && (in_sizes[2] == NBATCH*CHN*40*40);
  if (interleaved) {
    for (int i = 0; i < 5; ++i) { cate[i] = (const float*)d_in[1 + 2*i]; kern[i] = (const float*)d_in[2 + 2*i]; }
  } else {
    for (int i = 0; i < 5; ++i) { cate[i] = (const float*)d_in[1 + i]; kern[i] = (const float*)d_in[6 + i]; }
  }
  float* outF = (float*)d_out;

  uint8_t* p = (uint8_t*)d_ws;
  auto alloc = [&](size_t bytes) -> void* {
    void* r = (void*)p;
    p += (bytes + 255) & ~(size_t)255;
    return r;
  };
  uint8_t*  zbase       = p;
  uint32_t* hist        = (uint32_t*)alloc((size_t)(NBATCH*NBINS + NBATCH)*4);
  uint32_t* cnt         = hist + NBATCH*NBINS;
  size_t    zbytes      = (size_t)(p - zbase);

  float*    scores_t    = (float*)   alloc((size_t)NBATCH*FLATN*4);
  int*      cutoff      = (int*)     alloc((size_t)NBATCH*4);
  float*    cval        = (float*)   alloc((size_t)NBATCH*CANDCAP*4);
  uint32_t* cidx        = (uint32_t*)alloc((size_t)NBATCH*CANDCAP*4);
  float*    vals        = (float*)   alloc((size_t)NBATCH*TOPN*4);
  int*      cellA       = (int*)     alloc((size_t)NBATCH*TOPN*4);
  int*      labelA      = (int*)     alloc((size_t)NBATCH*TOPN*4);
  float*    Kmat        = (float*)   alloc((size_t)NBATCH*TOPN*CHN*4);
  uint32_t* bits        = (uint32_t*)alloc((size_t)NBATCH*TOPN*512*4);
  float*    psum        = (float*)   alloc((size_t)GNB*NBATCH*TOPN*4);
  float*    pseg        = (float*)   alloc((size_t)GNB*NBATCH*TOPN*4);
  float*    summ        = (float*)   alloc((size_t)NBATCH*TOPN*4);
  float*    scores      = (float*)   alloc((size_t)NBATCH*TOPN*4);
  int*      keepA       = (int*)     alloc((size_t)NBATCH*TOPN*4);
  int*      order       = (int*)     alloc((size_t)NBATCH*TOPN*4);
  float*    dmat        = (float*)   alloc((size_t)NBATCH*TOPN*TOPN*4);
  float*    comp        = (float*)   alloc((size_t)NBATCH*TOPN*4);
  float*    s2          = (float*)   alloc((size_t)NBATCH*TOPN*4);
  int*      selrow      = (int*)     alloc((size_t)NBATCH*MAXM*4);
  unsigned short* sigb  = (unsigned short*)alloc((size_t)NBATCH*SROWS*HWN*2);
  (void)ws_size; (void)out_size;

  hipMemsetAsync(zbase, 0, zbytes, stream);
  hipLaunchKernelGGL(k1_scores, dim3((NBATCH*FLATN + 255)/256), dim3(256), 0, stream,
                     cate[0], cate[1], cate[2], cate[3], cate[4], scores_t, hist);
  hipLaunchKernelGGL(k2_cutoff, dim3(NBATCH), dim3(1024), 0, stream, hist, cutoff);
  hipLaunchKernelGGL(k3_gather, dim3((NBATCH*FLATN + 255)/256), dim3(256), 0, stream,
                     scores_t, cutoff, cnt, cval, cidx);
  hipLaunchKernelGGL(k4_sort, dim3(NBATCH), dim3(512), 0, stream, cnt, cval, cidx, vals, cellA, labelA);
  hipLaunchKernelGGL(k5_kmat, dim3((NBATCH*TOPN*CHN + 255)/256), dim3(256), 0, stream,
                     kern[0], kern[1], kern[2], kern[3], kern[4], cellA, Kmat);
  hipLaunchKernelGGL(k6_gemm1, dim3(GNB, (TOPN+BM-1)/BM, NBATCH), dim3(256), 0, stream,
                     Kmat, mf, sigb, bits, psum, pseg);
  hipLaunchKernelGGL(k78_stats_order, dim3(NBATCH), dim3(512), 0, stream,
                     psum, pseg, vals, cellA, summ, scores, keepA, order, comp);
  hipLaunchKernelGGL(k9_dmat, dim3(TOPN, NBATCH), dim3(256), 0, stream,
                     bits, order, labelA, keepA, summ, dmat, comp);
  hipLaunchKernelGGL(k10_coef, dim3(TOPN, NBATCH), dim3(512), 0, stream,
                     dmat, comp, scores, order, keepA, s2);
  hipLaunchKernelGGL(k11_top100, dim3(NBATCH), dim3(512), 0, stream, s2, order, labelA, outF, selrow);
  hipLaunchKernelGGL(k13_upsample, dim3((NBATCH*MAXM*OUTH*(OUTW/4) + 255)/256), dim3(256), 0, stream,
                     sigb, selrow, outF);
}

// Round 15
// 369.245 us; speedup vs baseline: 1.1396x; 1.1396x over previous
//
#include <hip/hip_runtime.h>
#include <math.h>
#include <stdint.h>

#define NBATCH 2
#define NC 80
#define CHN 256
#define HMM 128
#define HWN (HMM*HMM)
#define NCELL 3872
#define FLATN (NCELL*NC)
#define TOPN 500
#define SROWS 512
#define MAXM 100
#define OUTH 512
#define OUTW 512
#define NBINS 1024
#define CANDCAP 1024
#define BM 128
#define BN 128
#define BK 16
#define GNB (HWN/BN)   // 128 N-blocks per row

__device__ __forceinline__ float sigmoidf_(float x){ return 1.0f/(1.0f+expf(-x)); }
__device__ __forceinline__ unsigned short f2bf(float x){
  uint32_t u = __float_as_uint(x);
  uint32_t r = u + 0x7FFFu + ((u >> 16) & 1u);
  return (unsigned short)(r >> 16);
}
__device__ __forceinline__ float bf2f(unsigned short h){ return __uint_as_float(((uint32_t)h) << 16); }

__device__ __forceinline__ void cell_decode(int cell, int& lvl, int& g, int& y, int& x){
  int off;
  if (cell < 1600)      { lvl=0; g=40; off=0; }
  else if (cell < 2896) { lvl=1; g=36; off=1600; }
  else if (cell < 3472) { lvl=2; g=24; off=2896; }
  else if (cell < 3728) { lvl=3; g=16; off=3472; }
  else                  { lvl=4; g=12; off=3728; }
  int r = cell - off; y = r / g; x = r - y*g;
}

// Bitonic sort, descending; barrier only for j>=32 passes.
template<int N, int NT>
__device__ __forceinline__ void bitonic_desc(uint64_t* key){
  int tid = threadIdx.x;
  __syncthreads();
  for (int k = 2; k <= N; k <<= 1)
    for (int j = k >> 1; j > 0; j >>= 1) {
      if (j >= 32) __syncthreads();
      for (int e = tid; e < N; e += NT) {
        int l = e ^ j;
        if (l > e) {
          uint64_t a = key[e], c = key[l];
          bool up = ((e & k) == 0);
          if (up ? (a < c) : (a > c)) { key[e] = c; key[l] = a; }
        }
      }
    }
  __syncthreads();
}

// c-major ordering; per-block LDS histogram.
__global__ void k1_scores(const float* __restrict__ c0, const float* __restrict__ c1,
                          const float* __restrict__ c2, const float* __restrict__ c3,
                          const float* __restrict__ c4,
                          float* __restrict__ scores_t, uint32_t* __restrict__ hist){
  __shared__ uint32_t h[NBATCH*NBINS];
  int tid = threadIdx.x;
  for (int i = tid; i < NBATCH*NBINS; i += 256) h[i] = 0;
  __syncthreads();
  int t = blockIdx.x*blockDim.x + tid;
  if (t < NBATCH*FLATN) {
    int b = t / FLATN;
    int rem = t - b*FLATN;
    int c = rem / NCELL;
    int cell = rem - c*NCELL;
    int lvl,g,y,x; cell_decode(cell,lvl,g,y,x);
    const float* cp = lvl==0?c0:lvl==1?c1:lvl==2?c2:lvl==3?c3:c4;
    const float* base = cp + (size_t)(b*NC + c)*g*g;
    float raw = base[y*g + x];
    float m = raw;
    if (y > 0)          m = fmaxf(m, base[(y-1)*g + x]);
    if (x > 0)          m = fmaxf(m, base[y*g + x-1]);
    if (y > 0 && x > 0) m = fmaxf(m, base[(y-1)*g + x-1]);
    float s = (raw == m) ? sigmoidf_(raw) : 0.0f;
    scores_t[t] = s;
    if (s > 0.1f) {
      int bin = (int)(s * 1024.0f); if (bin > NBINS-1) bin = NBINS-1;
      atomicAdd(&h[b*NBINS + bin], 1u);
    }
  }
  __syncthreads();
  for (int i = tid; i < NBATCH*NBINS; i += 256) {
    uint32_t v = h[i];
    if (v) atomicAdd(&hist[i], v);
  }
}

__global__ __launch_bounds__(1024) void k2_cutoff(const uint32_t* __restrict__ hist, int* __restrict__ cutoff){
  __shared__ uint32_t h[NBINS];
  int b = blockIdx.x;
  h[threadIdx.x] = hist[b*NBINS + threadIdx.x];
  __syncthreads();
  if (threadIdx.x == 0) {
    int acc = 0; int cut = 0;
    for (int d = NBINS-1; d >= 0; --d) {
      acc += (int)h[d];
      if (acc >= TOPN) { cut = d; break; }
    }
    cutoff[b] = cut;
  }
}

__global__ void k3_gather(const float* __restrict__ scores_t, const int* __restrict__ cutoff,
                          uint32_t* __restrict__ cnt, float* __restrict__ cval, uint32_t* __restrict__ cidx){
  int t = blockIdx.x*blockDim.x + threadIdx.x;
  if (t >= NBATCH*FLATN) return;
  int b = t / FLATN;
  int rem = t - b*FLATN;
  int c = rem / NCELL;
  int cell = rem - c*NCELL;
  float v = scores_t[t];
  if (v > 0.1f) {
    int bin = (int)(v * 1024.0f); if (bin > NBINS-1) bin = NBINS-1;
    if (bin >= cutoff[b]) {
      uint32_t p = atomicAdd(&cnt[b], 1u);
      if (p < CANDCAP) { cval[b*CANDCAP+p] = v; cidx[b*CANDCAP+p] = (uint32_t)(cell*NC + c); }
    }
  }
}

__global__ __launch_bounds__(512) void k4_sort(const uint32_t* __restrict__ cnt,
        const float* __restrict__ cval, const uint32_t* __restrict__ cidx,
        float* __restrict__ vals, int* __restrict__ cellA, int* __restrict__ labelA){
  __shared__ uint64_t key[CANDCAP];
  int b = blockIdx.x; int tid = threadIdx.x;
  int n = (int)cnt[b]; if (n > CANDCAP) n = CANDCAP;
  for (int e = tid; e < CANDCAP; e += 512) {
    uint64_t k = 0;
    if (e < n)
      k = ((uint64_t)__float_as_uint(cval[b*CANDCAP+e]) << 32) |
          (uint64_t)(0xFFFFFFFFu - cidx[b*CANDCAP+e]);
    key[e] = k;
  }
  bitonic_desc<CANDCAP,512>(key);
  for (int r = tid; r < TOPN; r += 512) {
    uint64_t k = key[r];
    if ((k >> 32) == 0) { vals[b*TOPN+r] = -1.0f; cellA[b*TOPN+r] = 0; labelA[b*TOPN+r] = 0; }
    else {
      uint32_t idx = 0xFFFFFFFFu - (uint32_t)(k & 0xFFFFFFFFu);
      vals[b*TOPN+r]   = __uint_as_float((uint32_t)(k >> 32));
      cellA[b*TOPN+r]  = (int)(idx / NC);
      labelA[b*TOPN+r] = (int)(idx % NC);
    }
  }
}

__global__ void k5_kmat(const float* __restrict__ k0p, const float* __restrict__ k1p,
                        const float* __restrict__ k2p, const float* __restrict__ k3p,
                        const float* __restrict__ k4p,
                        const int* __restrict__ cellA, float* __restrict__ Kmat){
  int t = blockIdx.x*blockDim.x + threadIdx.x;
  if (t >= NBATCH*TOPN*CHN) return;
  int b = t / (TOPN*CHN); int rem = t - b*(TOPN*CHN);
  int k = rem / CHN; int c = rem - k*CHN;
  int cell = cellA[b*TOPN + k];
  int lvl,g,y,x; cell_decode(cell,lvl,g,y,x);
  const float* kp = lvl==0?k0p:lvl==1?k1p:lvl==2?k2p:lvl==3?k3p:k4p;
  Kmat[t] = kp[((size_t)(b*CHN + c)*g + y)*g + x];
}

// r13 k6 (known-good 136us): 128x128 tile, 8x8 micro-tile, BK=16, LDS double-buffer,
// A transposed+swizzled, B through LDS; GNB-major psum/pseg; bf16 sigb.
__global__ __launch_bounds__(256) void k6_gemm1(const float* __restrict__ Kmat, const float* __restrict__ mf,
        unsigned short* __restrict__ sigb, uint32_t* __restrict__ bits,
        float* __restrict__ psum, float* __restrict__ pseg){
  __shared__ alignas(16) float As[2][BK][BM+4];
  __shared__ alignas(16) float Bs[2][BK][BN];
  int tid = threadIdx.x;
  int nb = blockIdx.x, mb = blockIdx.y, b = blockIdx.z;
  int row0 = mb*BM, col0 = nb*BN;
  int tx = tid & 15, ty = tid >> 4;

  int ar[2], aq[2], bkk[2], bcc[2];
  #pragma unroll
  for (int i = 0; i < 2; ++i) {
    int e = i*256 + tid;
    ar[i] = e >> 2; aq[i] = e & 3;
    bkk[i] = e >> 5; bcc[i] = e & 31;
  }
  float4 pa[2], pb[2];
  const float4 z4 = make_float4(0.f,0.f,0.f,0.f);
  #pragma unroll
  for (int i = 0; i < 2; ++i) {
    int rr = row0 + ar[i];
    pa[i] = (rr < TOPN) ? *(const float4*)&Kmat[((size_t)b*TOPN + rr)*CHN + aq[i]*4] : z4;
    pb[i] = *(const float4*)&mf[((size_t)b*CHN + bkk[i])*HWN + col0 + bcc[i]*4];
  }
  #pragma unroll
  for (int i = 0; i < 2; ++i) {
    int colA = ar[i] ^ (aq[i] << 2);
    As[0][aq[i]*4+0][colA] = pa[i].x;
    As[0][aq[i]*4+1][colA] = pa[i].y;
    As[0][aq[i]*4+2][colA] = pa[i].z;
    As[0][aq[i]*4+3][colA] = pa[i].w;
    *(float4*)&Bs[0][bkk[i]][bcc[i]*4] = pb[i];
  }
  __syncthreads();

  float acc[8][8];
  #pragma unroll
  for (int i=0;i<8;i++)
    #pragma unroll
    for(int j=0;j<8;j++) acc[i][j]=0.f;

  int cur = 0;
  for (int k0 = 0; k0 < CHN; k0 += BK) {
    bool more = (k0 + BK < CHN);
    if (more) {
      int k0n = k0 + BK;
      #pragma unroll
      for (int i = 0; i < 2; ++i) {
        int rr = row0 + ar[i];
        pa[i] = (rr < TOPN) ? *(const float4*)&Kmat[((size_t)b*TOPN + rr)*CHN + k0n + aq[i]*4] : z4;
        pb[i] = *(const float4*)&mf[((size_t)b*CHN + k0n + bkk[i])*HWN + col0 + bcc[i]*4];
      }
    }
    #pragma unroll 4
    for (int kk = 0; kk < BK; ++kk) {
      int s = (kk >> 2) << 2;
      float4 a0 = *(float4*)&As[cur][kk][(ty*8) ^ s];
      float4 a1 = *(float4*)&As[cur][kk][(ty*8+4) ^ s];
      float4 b0 = *(float4*)&Bs[cur][kk][tx*4];
      float4 b1 = *(float4*)&Bs[cur][kk][64+tx*4];
      float av[8] = {a0.x,a0.y,a0.z,a0.w,a1.x,a1.y,a1.z,a1.w};
      #pragma unroll
      for (int i = 0; i < 8; ++i) {
        acc[i][0] += av[i]*b0.x; acc[i][1] += av[i]*b0.y; acc[i][2] += av[i]*b0.z; acc[i][3] += av[i]*b0.w;
        acc[i][4] += av[i]*b1.x; acc[i][5] += av[i]*b1.y; acc[i][6] += av[i]*b1.z; acc[i][7] += av[i]*b1.w;
      }
    }
    if (more) {
      int nxt = cur ^ 1;
      #pragma unroll
      for (int i = 0; i < 2; ++i) {
        int colA = ar[i] ^ (aq[i] << 2);
        As[nxt][aq[i]*4+0][colA] = pa[i].x;
        As[nxt][aq[i]*4+1][colA] = pa[i].y;
        As[nxt][aq[i]*4+2][colA] = pa[i].z;
        As[nxt][aq[i]*4+3][colA] = pa[i].w;
        *(float4*)&Bs[nxt][bkk[i]][bcc[i]*4] = pb[i];
      }
      __syncthreads();
      cur = nxt;
    }
  }
  // epilogue
  #pragma unroll
  for (int i = 0; i < 8; ++i) {
    int r = row0 + ty*8 + i;
    float se = 0.f; int cc = 0;
    #pragma unroll
    for (int q = 0; q < 2; ++q) {
      float4 sv;
      sv.x = sigmoidf_(acc[i][q*4+0]);
      sv.y = sigmoidf_(acc[i][q*4+1]);
      sv.z = sigmoidf_(acc[i][q*4+2]);
      sv.w = sigmoidf_(acc[i][q*4+3]);
      uint32_t m = 0;
      if (sv.x > 0.5f) { m |= 1u; se += sv.x; cc++; }
      if (sv.y > 0.5f) { m |= 2u; se += sv.y; cc++; }
      if (sv.z > 0.5f) { m |= 4u; se += sv.z; cc++; }
      if (sv.w > 0.5f) { m |= 8u; se += sv.w; cc++; }
      uint32_t wrd = m << ((tx & 7)*4);
      wrd |= __shfl_xor(wrd, 1);
      wrd |= __shfl_xor(wrd, 2);
      wrd |= __shfl_xor(wrd, 4);
      if ((tx & 7) == 0 && r < TOPN)
        bits[((size_t)b*TOPN + r)*512 + nb*4 + q*2 + (tx>>3)] = wrd;
      ushort4 sb;
      sb.x = f2bf(sv.x); sb.y = f2bf(sv.y); sb.z = f2bf(sv.z); sb.w = f2bf(sv.w);
      *(ushort4*)&sigb[((size_t)b*SROWS + r)*HWN + col0 + q*64 + tx*4] = sb;
    }
    #pragma unroll
    for (int d = 1; d < 16; d <<= 1) {
      se += __shfl_xor(se, d);
      cc += __shfl_xor(cc, d);
    }
    if (tx == 0 && r < TOPN) {
      psum[(size_t)nb*(NBATCH*TOPN) + b*TOPN + r] = (float)cc;
      pseg[(size_t)nb*(NBATCH*TOPN) + b*TOPN + r] = se;
    }
  }
}

// rowstats + order-sort; zeroes comp
__global__ __launch_bounds__(512) void k78_stats_order(const float* __restrict__ psum, const float* __restrict__ pseg,
        const float* __restrict__ vals, const int* __restrict__ cellA,
        float* __restrict__ summ, float* __restrict__ scores, int* __restrict__ keepA,
        int* __restrict__ order, float* __restrict__ comp){
  __shared__ uint64_t key[512];
  int b = blockIdx.x, tid = threadIdx.x;
  uint64_t k = 0;
  if (tid < TOPN) {
    int t = b*TOPN + tid;
    comp[t] = 0.f;
    float sc = 0.f, sg = 0.f;
    for (int i = 0; i < GNB; ++i) {
      sc += psum[(size_t)i*(NBATCH*TOPN) + t];
      sg += pseg[(size_t)i*(NBATCH*TOPN) + t];
    }
    float v = vals[t];
    int cell = cellA[t];
    int lvl,g,y,x; cell_decode(cell,lvl,g,y,x);
    float stride = (lvl<=1)?8.f:(lvl==2)?16.f:32.f;
    bool keep = (v > 0.1f) && (sc > stride);
    float seg = sg / fmaxf(sc, 1e-6f);
    summ[t] = sc;
    float s = keep ? v*seg : 0.f;
    scores[t] = s;
    keepA[t] = keep ? 1 : 0;
    k = ((uint64_t)__float_as_uint(s) << 32) | (uint64_t)(0xFFFFFFFFu - (uint32_t)tid);
  }
  key[tid] = k;
  bitonic_desc<512,512>(key);
  if (tid < TOPN) order[b*TOPN+tid] = (int)(0xFFFFFFFFu - (uint32_t)(key[tid] & 0xFFFFFFFFu));
}

// one block per (i,b); dense row-major dmat rows + comp[j] atomicMax
__global__ __launch_bounds__(256) void k9_dmat(const uint32_t* __restrict__ bitsG,
        const int* __restrict__ order, const int* __restrict__ labelA, const int* __restrict__ keepA,
        const float* __restrict__ summ, float* __restrict__ dmat, float* __restrict__ comp){
  __shared__ uint32_t rowb[512];
  int i = blockIdx.x, b = blockIdx.y, tid = threadIdx.x;
  int oi = order[b*TOPN + i];
  int keep_i = keepA[b*TOPN + oi];
  float si = summ[b*TOPN + oi];
  int li = labelA[b*TOPN + oi];
  if (keep_i)
    for (int w = tid; w < 512; w += 256) rowb[w] = bitsG[((size_t)b*TOPN + oi)*512 + w];
  __syncthreads();
  float* drow = dmat + ((size_t)b*TOPN + i)*TOPN;
  for (int j = tid; j < TOPN; j += 256) {
    float v = 0.f;
    if (keep_i && j > i) {
      int oj = order[b*TOPN + j];
      if (keepA[b*TOPN + oj] && labelA[b*TOPN + oj] == li) {
        const uint4* rj = (const uint4*)&bitsG[((size_t)b*TOPN + oj)*512];
        const uint4* ri = (const uint4*)rowb;
        int cc = 0;
        for (int w = 0; w < 128; ++w) {
          uint4 x = rj[w], y = ri[w];
          cc += __popc(x.x & y.x) + __popc(x.y & y.y) + __popc(x.z & y.z) + __popc(x.w & y.w);
        }
        float sj = summ[b*TOPN + oj];
        float inter = (float)cc;
        v = inter / fmaxf(si + sj - inter, 1e-6f);
      }
    }
    drow[j] = v;
    if (v > 0.f) atomicMax((int*)&comp[b*TOPN + j], __float_as_int(v));
  }
}

// coef + s2; LAST BLOCK (block-level fence, validated in r12) runs top-100 (k11 folded)
__global__ __launch_bounds__(512) void k10_coef(const float* __restrict__ dmat, const float* __restrict__ comp,
        const float* __restrict__ scores, const int* __restrict__ order, const int* __restrict__ keepA,
        const int* __restrict__ labelA,
        float* __restrict__ s2, uint32_t* __restrict__ ctr,
        float* __restrict__ outF, int* __restrict__ selrow){
  __shared__ float red[8];
  __shared__ uint64_t key[512];
  __shared__ int lastF;
  int j = blockIdx.x, b = blockIdx.y, tid = threadIdx.x;
  float mn = 1e30f;
  if (tid < TOPN) {
    float d = dmat[((size_t)b*TOPN + tid)*TOPN + j];
    float c = comp[b*TOPN + tid];
    mn = expf(-2.0f*d*d) / expf(-2.0f*c*c);
  }
  #pragma unroll
  for (int d = 1; d < 64; d <<= 1) mn = fminf(mn, __shfl_xor(mn, d));
  if ((tid & 63) == 0) red[tid >> 6] = mn;
  __syncthreads();
  if (tid == 0) {
    mn = red[0];
    #pragma unroll
    for (int w = 1; w < 8; ++w) mn = fminf(mn, red[w]);
    int oj = order[b*TOPN+j];
    float s = scores[b*TOPN+oj] * mn;
    bool ok = (s >= 0.05f) && (s >= 0.1f) && (keepA[b*TOPN+oj] != 0);
    s2[b*TOPN+j] = ok ? s : 0.f;
    __threadfence();
    lastF = (atomicAdd(ctr, 1u) == (uint32_t)(TOPN*NBATCH - 1)) ? 1 : 0;
  }
  __syncthreads();
  if (!lastF) return;
  for (int b2 = 0; b2 < NBATCH; ++b2) {
    uint64_t k = 0;
    if (tid < TOPN) {
      float v = atomicAdd((float*)&s2[b2*TOPN + tid], 0.0f);
      k = ((uint64_t)__float_as_uint(v) << 32) | (uint64_t)(0xFFFFFFFFu - (uint32_t)tid);
    }
    key[tid] = k;
    bitonic_desc<512,512>(key);
    if (tid < MAXM) {
      uint64_t kk = key[tid];
      float v = __uint_as_float((uint32_t)(kk >> 32));
      int jj = (int)(0xFFFFFFFFu - (uint32_t)(kk & 0xFFFFFFFFu));
      if (jj < 0 || jj >= TOPN) { jj = 0; v = 0.f; }
      int orow = order[b2*TOPN + jj];
      float lab = (v > 0.f) ? (float)labelA[b2*TOPN + orow] : -1.0f;
      size_t maskCount = (size_t)NBATCH*MAXM*OUTH*OUTW;
      outF[maskCount + (size_t)b2*MAXM + tid] = lab;
      outF[maskCount + (size_t)NBATCH*MAXM + (size_t)b2*MAXM + tid] = v;
      selrow[b2*MAXM + tid] = orow;
    }
    __syncthreads();
  }
}

__global__ void k13_upsample(const unsigned short* __restrict__ sigb, const int* __restrict__ selrow,
                             float* __restrict__ outF){
  int t = blockIdx.x*blockDim.x + threadIdx.x;
  const int XG = OUTW/4;
  int total = NBATCH*MAXM*OUTH*XG;
  if (t >= total) return;
  int xg = t % XG;
  int tmp = t / XG;
  int Y = tmp % OUTH;
  int tmp2 = tmp / OUTH;
  int r = tmp2 % MAXM;
  int b = tmp2 / MAXM;
  size_t maskCount = (size_t)NBATCH*MAXM*OUTH*OUTW;
  float fv = outF[maskCount + (size_t)NBATCH*MAXM + (size_t)b*MAXM + r];
  float4 o = make_float4(0.f,0.f,0.f,0.f);
  if (fv > 0.f) {
    const unsigned short* sm = sigb + ((size_t)b*SROWS + selrow[b*MAXM + r])*HWN;
    const float SC = (float)(127.0/511.0);
    float fy = (float)Y * SC;
    int ly = (int)floorf(fy); if (ly < 0) ly = 0; if (ly > HMM-1) ly = HMM-1;
    int hy = ly+1 < HMM ? ly+1 : HMM-1;
    float wy = fy - (float)ly;
    float res[4];
    #pragma unroll
    for (int u = 0; u < 4; ++u) {
      int X = xg*4 + u;
      float fx = (float)X * SC;
      int lx = (int)floorf(fx); if (lx < 0) lx = 0; if (lx > HMM-1) lx = HMM-1;
      int hx = lx+1 < HMM ? lx+1 : HMM-1;
      float wx = fx - (float)lx;
      float a = (1.f-wy)*bf2f(sm[ly*HMM+lx]) + wy*bf2f(sm[hy*HMM+lx]);
      float c = (1.f-wy)*bf2f(sm[ly*HMM+hx]) + wy*bf2f(sm[hy*HMM+hx]);
      float v = (1.f-wx)*a + wx*c;
      res[u] = (v > 0.5f) ? 1.f : 0.f;
    }
    o = make_float4(res[0],res[1],res[2],res[3]);
  }
  *(float4*)&outF[(((size_t)b*MAXM + r)*OUTH + Y)*OUTW + xg*4] = o;
}

extern "C" void kernel_launch(void* const* d_in, const int* in_sizes, int n_in,
                              void* d_out, int out_size, void* d_ws, size_t ws_size,
                              hipStream_t stream) {
  const float* mf = (const float*)d_in[0];
  const float *cate[5], *kern[5];
  bool interleaved = (n_in > 2) && (in_sizes[2] == NBATCH*CHN*40*40);
  if (interleaved) {
    for (int i = 0; i < 5; ++i) { cate[i] = (const float*)d_in[1 + 2*i]; kern[i] = (const float*)d_in[2 + 2*i]; }
  } else {
    for (int i = 0; i < 5; ++i) { cate[i] = (const float*)d_in[1 + i]; kern[i] = (const float*)d_in[6 + i]; }
  }
  float* outF = (float*)d_out;

  uint8_t* p = (uint8_t*)d_ws;
  auto alloc = [&](size_t bytes) -> void* {
    void* r = (void*)p;
    p += (bytes + 255) & ~(size_t)255;
    return r;
  };
  uint8_t*  zbase       = p;
  uint32_t* hist        = (uint32_t*)alloc((size_t)(NBATCH*NBINS + NBATCH + 1)*4);
  uint32_t* cnt         = hist + NBATCH*NBINS;
  uint32_t* ctr10       = cnt + NBATCH;
  size_t    zbytes      = (size_t)(p - zbase);

  float*    scores_t    = (float*)   alloc((size_t)NBATCH*FLATN*4);
  int*      cutoff      = (int*)     alloc((size_t)NBATCH*4);
  float*    cval        = (float*)   alloc((size_t)NBATCH*CANDCAP*4);
  uint32_t* cidx        = (uint32_t*)alloc((size_t)NBATCH*CANDCAP*4);
  float*    vals        = (float*)   alloc((size_t)NBATCH*TOPN*4);
  int*      cellA       = (int*)     alloc((size_t)NBATCH*TOPN*4);
  int*      labelA      = (int*)     alloc((size_t)NBATCH*TOPN*4);
  float*    Kmat        = (float*)   alloc((size_t)NBATCH*TOPN*CHN*4);
  uint32_t* bits        = (uint32_t*)alloc((size_t)NBATCH*TOPN*512*4);
  float*    psum        = (float*)   alloc((size_t)GNB*NBATCH*TOPN*4);
  float*    pseg        = (float*)   alloc((size_t)GNB*NBATCH*TOPN*4);
  float*    summ        = (float*)   alloc((size_t)NBATCH*TOPN*4);
  float*    scores      = (float*)   alloc((size_t)NBATCH*TOPN*4);
  int*      keepA       = (int*)     alloc((size_t)NBATCH*TOPN*4);
  int*      order       = (int*)     alloc((size_t)NBATCH*TOPN*4);
  float*    dmat        = (float*)   alloc((size_t)NBATCH*TOPN*TOPN*4);
  float*    comp        = (float*)   alloc((size_t)NBATCH*TOPN*4);
  float*    s2          = (float*)   alloc((size_t)NBATCH*TOPN*4);
  int*      selrow      = (int*)     alloc((size_t)NBATCH*MAXM*4);
  unsigned short* sigb  = (unsigned short*)alloc((size_t)NBATCH*SROWS*HWN*2);
  (void)ws_size; (void)out_size;

  hipMemsetAsync(zbase, 0, zbytes, stream);
  hipLaunchKernelGGL(k1_scores, dim3((NBATCH*FLATN + 255)/256), dim3(256), 0, stream,
                     cate[0], cate[1], cate[2], cate[3], cate[4], scores_t, hist);
  hipLaunchKernelGGL(k2_cutoff, dim3(NBATCH), dim3(1024), 0, stream, hist, cutoff);
  hipLaunchKernelGGL(k3_gather, dim3((NBATCH*FLATN + 255)/256), dim3(256), 0, stream,
                     scores_t, cutoff, cnt, cval, cidx);
  hipLaunchKernelGGL(k4_sort, dim3(NBATCH), dim3(512), 0, stream, cnt, cval, cidx, vals, cellA, labelA);
  hipLaunchKernelGGL(k5_kmat, dim3((NBATCH*TOPN*CHN + 255)/256), dim3(256), 0, stream,
                     kern[0], kern[1], kern[2], kern[3], kern[4], cellA, Kmat);
  hipLaunchKernelGGL(k6_gemm1, dim3(GNB, (TOPN+BM-1)/BM, NBATCH), dim3(256), 0, stream,
                     Kmat, mf, sigb, bits, psum, pseg);
  hipLaunchKernelGGL(k78_stats_order, dim3(NBATCH), dim3(512), 0, stream,
                     psum, pseg, vals, cellA, summ, scores, keepA, order, comp);
  hipLaunchKernelGGL(k9_dmat, dim3(TOPN, NBATCH), dim3(256), 0, stream,
                     bits, order, labelA, keepA, summ, dmat, comp);
  hipLaunchKernelGGL(k10_coef, dim3(TOPN, NBATCH), dim3(512), 0, stream,
                     dmat, comp, scores, order, keepA, labelA, s2, ctr10, outF, selrow);
  hipLaunchKernelGGL(k13_upsample, dim3((NBATCH*MAXM*OUTH*(OUTW/4) + 255)/256), dim3(256), 0, stream,
                     sigb, selrow, outF);
}

// Round 16
// 340.414 us; speedup vs baseline: 1.2361x; 1.0847x over previous
//
#include <hip/hip_runtime.h>
#include <math.h>
#include <stdint.h>

#define NBATCH 2
#define NC 80
#define CHN 256
#define HMM 128
#define HWN (HMM*HMM)
#define NCELL 3872
#define FLATN (NCELL*NC)
#define TOPN 500
#define SROWS 512
#define MAXM 100
#define OUTH 512
#define OUTW 512
#define NBINS 1024
#define CANDCAP 1024
#define BM 128
#define BN 128
#define BK 16
#define GNB (HWN/BN)   // 128 N-blocks per row

__device__ __forceinline__ float sigmoidf_(float x){ return 1.0f/(1.0f+expf(-x)); }
__device__ __forceinline__ unsigned short f2bf(float x){
  uint32_t u = __float_as_uint(x);
  uint32_t r = u + 0x7FFFu + ((u >> 16) & 1u);
  return (unsigned short)(r >> 16);
}
__device__ __forceinline__ float bf2f(unsigned short h){ return __uint_as_float(((uint32_t)h) << 16); }

__device__ __forceinline__ void cell_decode(int cell, int& lvl, int& g, int& y, int& x){
  int off;
  if (cell < 1600)      { lvl=0; g=40; off=0; }
  else if (cell < 2896) { lvl=1; g=36; off=1600; }
  else if (cell < 3472) { lvl=2; g=24; off=2896; }
  else if (cell < 3728) { lvl=3; g=16; off=3472; }
  else                  { lvl=4; g=12; off=3728; }
  int r = cell - off; y = r / g; x = r - y*g;
}

// Bitonic sort, descending; barrier only for j>=32 passes.
template<int N, int NT>
__device__ __forceinline__ void bitonic_desc(uint64_t* key){
  int tid = threadIdx.x;
  __syncthreads();
  for (int k = 2; k <= N; k <<= 1)
    for (int j = k >> 1; j > 0; j >>= 1) {
      if (j >= 32) __syncthreads();
      for (int e = tid; e < N; e += NT) {
        int l = e ^ j;
        if (l > e) {
          uint64_t a = key[e], c = key[l];
          bool up = ((e & k) == 0);
          if (up ? (a < c) : (a > c)) { key[e] = c; key[l] = a; }
        }
      }
    }
  __syncthreads();
}

// c-major ordering; per-block LDS histogram.
__global__ void k1_scores(const float* __restrict__ c0, const float* __restrict__ c1,
                          const float* __restrict__ c2, const float* __restrict__ c3,
                          const float* __restrict__ c4,
                          float* __restrict__ scores_t, uint32_t* __restrict__ hist){
  __shared__ uint32_t h[NBATCH*NBINS];
  int tid = threadIdx.x;
  for (int i = tid; i < NBATCH*NBINS; i += 256) h[i] = 0;
  __syncthreads();
  int t = blockIdx.x*blockDim.x + tid;
  if (t < NBATCH*FLATN) {
    int b = t / FLATN;
    int rem = t - b*FLATN;
    int c = rem / NCELL;
    int cell = rem - c*NCELL;
    int lvl,g,y,x; cell_decode(cell,lvl,g,y,x);
    const float* cp = lvl==0?c0:lvl==1?c1:lvl==2?c2:lvl==3?c3:c4;
    const float* base = cp + (size_t)(b*NC + c)*g*g;
    float raw = base[y*g + x];
    float m = raw;
    if (y > 0)          m = fmaxf(m, base[(y-1)*g + x]);
    if (x > 0)          m = fmaxf(m, base[y*g + x-1]);
    if (y > 0 && x > 0) m = fmaxf(m, base[(y-1)*g + x-1]);
    float s = (raw == m) ? sigmoidf_(raw) : 0.0f;
    scores_t[t] = s;
    if (s > 0.1f) {
      int bin = (int)(s * 1024.0f); if (bin > NBINS-1) bin = NBINS-1;
      atomicAdd(&h[b*NBINS + bin], 1u);
    }
  }
  __syncthreads();
  for (int i = tid; i < NBATCH*NBINS; i += 256) {
    uint32_t v = h[i];
    if (v) atomicAdd(&hist[i], v);
  }
}

__global__ __launch_bounds__(1024) void k2_cutoff(const uint32_t* __restrict__ hist, int* __restrict__ cutoff){
  __shared__ uint32_t h[NBINS];
  int b = blockIdx.x;
  h[threadIdx.x] = hist[b*NBINS + threadIdx.x];
  __syncthreads();
  if (threadIdx.x == 0) {
    int acc = 0; int cut = 0;
    for (int d = NBINS-1; d >= 0; --d) {
      acc += (int)h[d];
      if (acc >= TOPN) { cut = d; break; }
    }
    cutoff[b] = cut;
  }
}

__global__ void k3_gather(const float* __restrict__ scores_t, const int* __restrict__ cutoff,
                          uint32_t* __restrict__ cnt, float* __restrict__ cval, uint32_t* __restrict__ cidx){
  int t = blockIdx.x*blockDim.x + threadIdx.x;
  if (t >= NBATCH*FLATN) return;
  int b = t / FLATN;
  int rem = t - b*FLATN;
  int c = rem / NCELL;
  int cell = rem - c*NCELL;
  float v = scores_t[t];
  if (v > 0.1f) {
    int bin = (int)(v * 1024.0f); if (bin > NBINS-1) bin = NBINS-1;
    if (bin >= cutoff[b]) {
      uint32_t p = atomicAdd(&cnt[b], 1u);
      if (p < CANDCAP) { cval[b*CANDCAP+p] = v; cidx[b*CANDCAP+p] = (uint32_t)(cell*NC + c); }
    }
  }
}

__global__ __launch_bounds__(512) void k4_sort(const uint32_t* __restrict__ cnt,
        const float* __restrict__ cval, const uint32_t* __restrict__ cidx,
        float* __restrict__ vals, int* __restrict__ cellA, int* __restrict__ labelA){
  __shared__ uint64_t key[CANDCAP];
  int b = blockIdx.x; int tid = threadIdx.x;
  int n = (int)cnt[b]; if (n > CANDCAP) n = CANDCAP;
  for (int e = tid; e < CANDCAP; e += 512) {
    uint64_t k = 0;
    if (e < n)
      k = ((uint64_t)__float_as_uint(cval[b*CANDCAP+e]) << 32) |
          (uint64_t)(0xFFFFFFFFu - cidx[b*CANDCAP+e]);
    key[e] = k;
  }
  bitonic_desc<CANDCAP,512>(key);
  for (int r = tid; r < TOPN; r += 512) {
    uint64_t k = key[r];
    if ((k >> 32) == 0) { vals[b*TOPN+r] = -1.0f; cellA[b*TOPN+r] = 0; labelA[b*TOPN+r] = 0; }
    else {
      uint32_t idx = 0xFFFFFFFFu - (uint32_t)(k & 0xFFFFFFFFu);
      vals[b*TOPN+r]   = __uint_as_float((uint32_t)(k >> 32));
      cellA[b*TOPN+r]  = (int)(idx / NC);
      labelA[b*TOPN+r] = (int)(idx % NC);
    }
  }
}

__global__ void k5_kmat(const float* __restrict__ k0p, const float* __restrict__ k1p,
                        const float* __restrict__ k2p, const float* __restrict__ k3p,
                        const float* __restrict__ k4p,
                        const int* __restrict__ cellA, float* __restrict__ Kmat){
  int t = blockIdx.x*blockDim.x + threadIdx.x;
  if (t >= NBATCH*TOPN*CHN) return;
  int b = t / (TOPN*CHN); int rem = t - b*(TOPN*CHN);
  int k = rem / CHN; int c = rem - k*CHN;
  int cell = cellA[b*TOPN + k];
  int lvl,g,y,x; cell_decode(cell,lvl,g,y,x);
  const float* kp = lvl==0?k0p:lvl==1?k1p:lvl==2?k2p:lvl==3?k3p:k4p;
  Kmat[t] = kp[((size_t)(b*CHN + c)*g + y)*g + x];
}

// 128x128 tile, 8x8 micro-tile, BK=16, LDS double-buffer; GNB-major psum/pseg; bf16 sigb.
__global__ __launch_bounds__(256) void k6_gemm1(const float* __restrict__ Kmat, const float* __restrict__ mf,
        unsigned short* __restrict__ sigb, uint32_t* __restrict__ bits,
        float* __restrict__ psum, float* __restrict__ pseg){
  __shared__ alignas(16) float As[2][BK][BM+4];
  __shared__ alignas(16) float Bs[2][BK][BN];
  int tid = threadIdx.x;
  int nb = blockIdx.x, mb = blockIdx.y, b = blockIdx.z;
  int row0 = mb*BM, col0 = nb*BN;
  int tx = tid & 15, ty = tid >> 4;

  int ar[2], aq[2], bkk[2], bcc[2];
  #pragma unroll
  for (int i = 0; i < 2; ++i) {
    int e = i*256 + tid;
    ar[i] = e >> 2; aq[i] = e & 3;
    bkk[i] = e >> 5; bcc[i] = e & 31;
  }
  float4 pa[2], pb[2];
  const float4 z4 = make_float4(0.f,0.f,0.f,0.f);
  #pragma unroll
  for (int i = 0; i < 2; ++i) {
    int rr = row0 + ar[i];
    pa[i] = (rr < TOPN) ? *(const float4*)&Kmat[((size_t)b*TOPN + rr)*CHN + aq[i]*4] : z4;
    pb[i] = *(const float4*)&mf[((size_t)b*CHN + bkk[i])*HWN + col0 + bcc[i]*4];
  }
  #pragma unroll
  for (int i = 0; i < 2; ++i) {
    int colA = ar[i] ^ (aq[i] << 2);
    As[0][aq[i]*4+0][colA] = pa[i].x;
    As[0][aq[i]*4+1][colA] = pa[i].y;
    As[0][aq[i]*4+2][colA] = pa[i].z;
    As[0][aq[i]*4+3][colA] = pa[i].w;
    *(float4*)&Bs[0][bkk[i]][bcc[i]*4] = pb[i];
  }
  __syncthreads();

  float acc[8][8];
  #pragma unroll
  for (int i=0;i<8;i++)
    #pragma unroll
    for(int j=0;j<8;j++) acc[i][j]=0.f;

  int cur = 0;
  for (int k0 = 0; k0 < CHN; k0 += BK) {
    bool more = (k0 + BK < CHN);
    if (more) {
      int k0n = k0 + BK;
      #pragma unroll
      for (int i = 0; i < 2; ++i) {
        int rr = row0 + ar[i];
        pa[i] = (rr < TOPN) ? *(const float4*)&Kmat[((size_t)b*TOPN + rr)*CHN + k0n + aq[i]*4] : z4;
        pb[i] = *(const float4*)&mf[((size_t)b*CHN + k0n + bkk[i])*HWN + col0 + bcc[i]*4];
      }
    }
    #pragma unroll 4
    for (int kk = 0; kk < BK; ++kk) {
      int s = (kk >> 2) << 2;
      float4 a0 = *(float4*)&As[cur][kk][(ty*8) ^ s];
      float4 a1 = *(float4*)&As[cur][kk][(ty*8+4) ^ s];
      float4 b0 = *(float4*)&Bs[cur][kk][tx*4];
      float4 b1 = *(float4*)&Bs[cur][kk][64+tx*4];
      float av[8] = {a0.x,a0.y,a0.z,a0.w,a1.x,a1.y,a1.z,a1.w};
      #pragma unroll
      for (int i = 0; i < 8; ++i) {
        acc[i][0] += av[i]*b0.x; acc[i][1] += av[i]*b0.y; acc[i][2] += av[i]*b0.z; acc[i][3] += av[i]*b0.w;
        acc[i][4] += av[i]*b1.x; acc[i][5] += av[i]*b1.y; acc[i][6] += av[i]*b1.z; acc[i][7] += av[i]*b1.w;
      }
    }
    if (more) {
      int nxt = cur ^ 1;
      #pragma unroll
      for (int i = 0; i < 2; ++i) {
        int colA = ar[i] ^ (aq[i] << 2);
        As[nxt][aq[i]*4+0][colA] = pa[i].x;
        As[nxt][aq[i]*4+1][colA] = pa[i].y;
        As[nxt][aq[i]*4+2][colA] = pa[i].z;
        As[nxt][aq[i]*4+3][colA] = pa[i].w;
        *(float4*)&Bs[nxt][bkk[i]][bcc[i]*4] = pb[i];
      }
      __syncthreads();
      cur = nxt;
    }
  }
  // epilogue
  #pragma unroll
  for (int i = 0; i < 8; ++i) {
    int r = row0 + ty*8 + i;
    float se = 0.f; int cc = 0;
    #pragma unroll
    for (int q = 0; q < 2; ++q) {
      float4 sv;
      sv.x = sigmoidf_(acc[i][q*4+0]);
      sv.y = sigmoidf_(acc[i][q*4+1]);
      sv.z = sigmoidf_(acc[i][q*4+2]);
      sv.w = sigmoidf_(acc[i][q*4+3]);
      uint32_t m = 0;
      if (sv.x > 0.5f) { m |= 1u; se += sv.x; cc++; }
      if (sv.y > 0.5f) { m |= 2u; se += sv.y; cc++; }
      if (sv.z > 0.5f) { m |= 4u; se += sv.z; cc++; }
      if (sv.w > 0.5f) { m |= 8u; se += sv.w; cc++; }
      uint32_t wrd = m << ((tx & 7)*4);
      wrd |= __shfl_xor(wrd, 1);
      wrd |= __shfl_xor(wrd, 2);
      wrd |= __shfl_xor(wrd, 4);
      if ((tx & 7) == 0 && r < TOPN)
        bits[((size_t)b*TOPN + r)*512 + nb*4 + q*2 + (tx>>3)] = wrd;
      ushort4 sb;
      sb.x = f2bf(sv.x); sb.y = f2bf(sv.y); sb.z = f2bf(sv.z); sb.w = f2bf(sv.w);
      *(ushort4*)&sigb[((size_t)b*SROWS + r)*HWN + col0 + q*64 + tx*4] = sb;
    }
    #pragma unroll
    for (int d = 1; d < 16; d <<= 1) {
      se += __shfl_xor(se, d);
      cc += __shfl_xor(cc, d);
    }
    if (tx == 0 && r < TOPN) {
      psum[(size_t)nb*(NBATCH*TOPN) + b*TOPN + r] = (float)cc;
      pseg[(size_t)nb*(NBATCH*TOPN) + b*TOPN + r] = se;
    }
  }
}

// rowstats + order-sort; zeroes comp
__global__ __launch_bounds__(512) void k78_stats_order(const float* __restrict__ psum, const float* __restrict__ pseg,
        const float* __restrict__ vals, const int* __restrict__ cellA,
        float* __restrict__ summ, float* __restrict__ scores, int* __restrict__ keepA,
        int* __restrict__ order, float* __restrict__ comp){
  __shared__ uint64_t key[512];
  int b = blockIdx.x, tid = threadIdx.x;
  uint64_t k = 0;
  if (tid < TOPN) {
    int t = b*TOPN + tid;
    comp[t] = 0.f;
    float sc = 0.f, sg = 0.f;
    for (int i = 0; i < GNB; ++i) {
      sc += psum[(size_t)i*(NBATCH*TOPN) + t];
      sg += pseg[(size_t)i*(NBATCH*TOPN) + t];
    }
    float v = vals[t];
    int cell = cellA[t];
    int lvl,g,y,x; cell_decode(cell,lvl,g,y,x);
    float stride = (lvl<=1)?8.f:(lvl==2)?16.f:32.f;
    bool keep = (v > 0.1f) && (sc > stride);
    float seg = sg / fmaxf(sc, 1e-6f);
    summ[t] = sc;
    float s = keep ? v*seg : 0.f;
    scores[t] = s;
    keepA[t] = keep ? 1 : 0;
    k = ((uint64_t)__float_as_uint(s) << 32) | (uint64_t)(0xFFFFFFFFu - (uint32_t)tid);
  }
  key[tid] = k;
  bitonic_desc<512,512>(key);
  if (tid < TOPN) order[b*TOPN+tid] = (int)(0xFFFFFFFFu - (uint32_t)(key[tid] & 0xFFFFFFFFu));
}

// one block per (i,b); dense row-major dmat rows + comp[j] atomicMax
__global__ __launch_bounds__(256) void k9_dmat(const uint32_t* __restrict__ bitsG,
        const int* __restrict__ order, const int* __restrict__ labelA, const int* __restrict__ keepA,
        const float* __restrict__ summ, float* __restrict__ dmat, float* __restrict__ comp){
  __shared__ uint32_t rowb[512];
  int i = blockIdx.x, b = blockIdx.y, tid = threadIdx.x;
  int oi = order[b*TOPN + i];
  int keep_i = keepA[b*TOPN + oi];
  float si = summ[b*TOPN + oi];
  int li = labelA[b*TOPN + oi];
  if (keep_i)
    for (int w = tid; w < 512; w += 256) rowb[w] = bitsG[((size_t)b*TOPN + oi)*512 + w];
  __syncthreads();
  float* drow = dmat + ((size_t)b*TOPN + i)*TOPN;
  for (int j = tid; j < TOPN; j += 256) {
    float v = 0.f;
    if (keep_i && j > i) {
      int oj = order[b*TOPN + j];
      if (keepA[b*TOPN + oj] && labelA[b*TOPN + oj] == li) {
        const uint4* rj = (const uint4*)&bitsG[((size_t)b*TOPN + oj)*512];
        const uint4* ri = (const uint4*)rowb;
        int cc = 0;
        for (int w = 0; w < 128; ++w) {
          uint4 x = rj[w], y = ri[w];
          cc += __popc(x.x & y.x) + __popc(x.y & y.y) + __popc(x.z & y.z) + __popc(x.w & y.w);
        }
        float sj = summ[b*TOPN + oj];
        float inter = (float)cc;
        v = inter / fmaxf(si + sj - inter, 1e-6f);
      }
    }
    drow[j] = v;
    if (v > 0.f) atomicMax((int*)&comp[b*TOPN + j], __float_as_int(v));
  }
}

// single-pass coef: block (j,b), 512 threads, tid=i
__global__ __launch_bounds__(512) void k10_coef(const float* __restrict__ dmat, const float* __restrict__ comp,
        const float* __restrict__ scores, const int* __restrict__ order, const int* __restrict__ keepA,
        float* __restrict__ s2){
  __shared__ float red[8];
  int j = blockIdx.x, b = blockIdx.y, tid = threadIdx.x;
  float mn = 1e30f;
  if (tid < TOPN) {
    float d = dmat[((size_t)b*TOPN + tid)*TOPN + j];
    float c = comp[b*TOPN + tid];
    mn = expf(-2.0f*d*d) / expf(-2.0f*c*c);
  }
  #pragma unroll
  for (int d = 1; d < 64; d <<= 1) mn = fminf(mn, __shfl_xor(mn, d));
  if ((tid & 63) == 0) red[tid >> 6] = mn;
  __syncthreads();
  if (tid == 0) {
    mn = red[0];
    #pragma unroll
    for (int w = 1; w < 8; ++w) mn = fminf(mn, red[w]);
    int oj = order[b*TOPN+j];
    float s = scores[b*TOPN+oj] * mn;
    bool ok = (s >= 0.05f) && (s >= 0.1f) && (keepA[b*TOPN+oj] != 0);
    s2[b*TOPN+j] = ok ? s : 0.f;
  }
}

__global__ __launch_bounds__(512) void k11_top100(const float* __restrict__ s2, const int* __restrict__ order,
        const int* __restrict__ labelA, float* __restrict__ outF, int* __restrict__ selrow){
  __shared__ uint64_t key[512];
  int b = blockIdx.x, tid = threadIdx.x;
  uint64_t k = 0;
  if (tid < TOPN)
    k = ((uint64_t)__float_as_uint(s2[b*TOPN+tid]) << 32) | (uint64_t)(0xFFFFFFFFu - (uint32_t)tid);
  key[tid] = k;
  bitonic_desc<512,512>(key);
  if (tid < MAXM) {
    uint64_t kk = key[tid];
    float v = __uint_as_float((uint32_t)(kk >> 32));
    int j = (int)(0xFFFFFFFFu - (uint32_t)(kk & 0xFFFFFFFFu));
    if (j < 0 || j >= TOPN) { j = 0; v = 0.f; }
    int orow = order[b*TOPN + j];
    float lab = (v > 0.f) ? (float)labelA[b*TOPN + orow] : -1.0f;
    size_t maskCount = (size_t)NBATCH*MAXM*OUTH*OUTW;
    outF[maskCount + (size_t)b*MAXM + tid] = lab;
    outF[maskCount + (size_t)NBATCH*MAXM + (size_t)b*MAXM + tid] = v;
    selrow[b*MAXM + tid] = orow;
  }
}

__global__ void k13_upsample(const unsigned short* __restrict__ sigb, const int* __restrict__ selrow,
                             float* __restrict__ outF){
  int t = blockIdx.x*blockDim.x + threadIdx.x;
  const int XG = OUTW/4;
  int total = NBATCH*MAXM*OUTH*XG;
  if (t >= total) return;
  int xg = t % XG;
  int tmp = t / XG;
  int Y = tmp % OUTH;
  int tmp2 = tmp / OUTH;
  int r = tmp2 % MAXM;
  int b = tmp2 / MAXM;
  size_t maskCount = (size_t)NBATCH*MAXM*OUTH*OUTW;
  float fv = outF[maskCount + (size_t)NBATCH*MAXM + (size_t)b*MAXM + r];
  float4 o = make_float4(0.f,0.f,0.f,0.f);
  if (fv > 0.f) {
    const unsigned short* sm = sigb + ((size_t)b*SROWS + selrow[b*MAXM + r])*HWN;
    const float SC = (float)(127.0/511.0);
    float fy = (float)Y * SC;
    int ly = (int)floorf(fy); if (ly < 0) ly = 0; if (ly > HMM-1) ly = HMM-1;
    int hy = ly+1 < HMM ? ly+1 : HMM-1;
    float wy = fy - (float)ly;
    float res[4];
    #pragma unroll
    for (int u = 0; u < 4; ++u) {
      int X = xg*4 + u;
      float fx = (float)X * SC;
      int lx = (int)floorf(fx); if (lx < 0) lx = 0; if (lx > HMM-1) lx = HMM-1;
      int hx = lx+1 < HMM ? lx+1 : HMM-1;
      float wx = fx - (float)lx;
      float a = (1.f-wy)*bf2f(sm[ly*HMM+lx]) + wy*bf2f(sm[hy*HMM+lx]);
      float c = (1.f-wy)*bf2f(sm[ly*HMM+hx]) + wy*bf2f(sm[hy*HMM+hx]);
      float v = (1.f-wx)*a + wx*c;
      res[u] = (v > 0.5f) ? 1.f : 0.f;
    }
    o = make_float4(res[0],res[1],res[2],res[3]);
  }
  *(float4*)&outF[(((size_t)b*MAXM + r)*OUTH + Y)*OUTW + xg*4] = o;
}

extern "C" void kernel_launch(void* const* d_in, const int* in_sizes, int n_in,
                              void* d_out, int out_size, void* d_ws, size_t ws_size,
                              hipStream_t stream) {
  const float* mf = (const float*)d_in[0];
  const float *cate[5], *kern[5];
  bool interleaved = (n_in > 2) && (in_sizes[2] == NBATCH*CHN*40*40);
  if (interleaved) {
    for (int i = 0; i < 5; ++i) { cate[i] = (const float*)d_in[1 + 2*i]; kern[i] = (const float*)d_in[2 + 2*i]; }
  } else {
    for (int i = 0; i < 5; ++i) { cate[i] = (const float*)d_in[1 + i]; kern[i] = (const float*)d_in[6 + i]; }
  }
  float* outF = (float*)d_out;

  uint8_t* p = (uint8_t*)d_ws;
  auto alloc = [&](size_t bytes) -> void* {
    void* r = (void*)p;
    p += (bytes + 255) & ~(size_t)255;
    return r;
  };
  uint8_t*  zbase       = p;
  uint32_t* hist        = (uint32_t*)alloc((size_t)(NBATCH*NBINS + NBATCH)*4);
  uint32_t* cnt         = hist + NBATCH*NBINS;
  size_t    zbytes      = (size_t)(p - zbase);

  float*    scores_t    = (float*)   alloc((size_t)NBATCH*FLATN*4);
  int*      cutoff      = (int*)     alloc((size_t)NBATCH*4);
  float*    cval        = (float*)   alloc((size_t)NBATCH*CANDCAP*4);
  uint32_t* cidx        = (uint32_t*)alloc((size_t)NBATCH*CANDCAP*4);
  float*    vals        = (float*)   alloc((size_t)NBATCH*TOPN*4);
  int*      cellA       = (int*)     alloc((size_t)NBATCH*TOPN*4);
  int*      labelA      = (int*)     alloc((size_t)NBATCH*TOPN*4);
  float*    Kmat        = (float*)   alloc((size_t)NBATCH*TOPN*CHN*4);
  uint32_t* bits        = (uint32_t*)alloc((size_t)NBATCH*TOPN*512*4);
  float*    psum        = (float*)   alloc((size_t)GNB*NBATCH*TOPN*4);
  float*    pseg        = (float*)   alloc((size_t)GNB*NBATCH*TOPN*4);
  float*    summ        = (float*)   alloc((size_t)NBATCH*TOPN*4);
  float*    scores      = (float*)   alloc((size_t)NBATCH*TOPN*4);
  int*      keepA       = (int*)     alloc((size_t)NBATCH*TOPN*4);
  int*      order       = (int*)     alloc((size_t)NBATCH*TOPN*4);
  float*    dmat        = (float*)   alloc((size_t)NBATCH*TOPN*TOPN*4);
  float*    comp        = (float*)   alloc((size_t)NBATCH*TOPN*4);
  float*    s2          = (float*)   alloc((size_t)NBATCH*TOPN*4);
  int*      selrow      = (int*)     alloc((size_t)NBATCH*MAXM*4);
  unsigned short* sigb  = (unsigned short*)alloc((size_t)NBATCH*SROWS*HWN*2);
  (void)ws_size; (void)out_size;

  hipMemsetAsync(zbase, 0, zbytes, stream);
  hipLaunchKernelGGL(k1_scores, dim3((NBATCH*FLATN + 255)/256), dim3(256), 0, stream,
                     cate[0], cate[1], cate[2], cate[3], cate[4], scores_t, hist);
  hipLaunchKernelGGL(k2_cutoff, dim3(NBATCH), dim3(1024), 0, stream, hist, cutoff);
  hipLaunchKernelGGL(k3_gather, dim3((NBATCH*FLATN + 255)/256), dim3(256), 0, stream,
                     scores_t, cutoff, cnt, cval, cidx);
  hipLaunchKernelGGL(k4_sort, dim3(NBATCH), dim3(512), 0, stream, cnt, cval, cidx, vals, cellA, labelA);
  hipLaunchKernelGGL(k5_kmat, dim3((NBATCH*TOPN*CHN + 255)/256), dim3(256), 0, stream,
                     kern[0], kern[1], kern[2], kern[3], kern[4], cellA, Kmat);
  hipLaunchKernelGGL(k6_gemm1, dim3(GNB, (TOPN+BM-1)/BM, NBATCH), dim3(256), 0, stream,
                     Kmat, mf, sigb, bits, psum, pseg);
  hipLaunchKernelGGL(k78_stats_order, dim3(NBATCH), dim3(512), 0, stream,
                     psum, pseg, vals, cellA, summ, scores, keepA, order, comp);
  hipLaunchKernelGGL(k9_dmat, dim3(TOPN, NBATCH), dim3(256), 0, stream,
                     bits, order, labelA, keepA, summ, dmat, comp);
  hipLaunchKernelGGL(k10_coef, dim3(TOPN, NBATCH), dim3(512), 0, stream,
                     dmat, comp, scores, order, keepA, s2);
  hipLaunchKernelGGL(k11_top100, dim3(NBATCH), dim3(512), 0, stream, s2, order, labelA, outF, selrow);
  hipLaunchKernelGGL(k13_upsample, dim3((NBATCH*MAXM*OUTH*(OUTW/4) + 255)/256), dim3(256), 0, stream,
                     sigb, selrow, outF);
}